// Round 17
// baseline (210.475 us; speedup 1.0000x reference)
//
#include <hip/hip_runtime.h>
#include <math.h>

#define NPTS   32768
#define CCH    128
#define FMH    480
#define FMW    640
#define PLANE  (FMH*FMW)
#define IMW    640
#define IMH    480
#define PPB    128         // points per accum block (2 lanes/point)
#define NBLKA  (NPTS/PPB)  // 256 accum blocks
#define NPART  27          // 6 (g) + 21 (H upper triangle)
#define MSTR   8           // per-pixel map stride (floats)
#define ROWB   256         // gQ bytes per pixel row (128 ch x 2 int8)
#define SCL    200.0f      // grad int8 scale (|gx| max ~0.57 -> 114 < 127)
#define INVS   0.005f      // 1/SCL

typedef float vfloat4 __attribute__((ext_vector_type(4)));

__device__ __forceinline__ float f4e(const float4& v, int i){
    return i==0 ? v.x : i==1 ? v.y : i==2 ? v.z : v.w;
}

__device__ __forceinline__ int q8(float v){
    return (int)rintf(fminf(fmaxf(v*SCL, -127.f), 127.f));
}

__device__ __forceinline__ unsigned pack2(float a0,float b0,float a1,float b1){
    return (unsigned)(q8(a0)&255) | ((unsigned)(q8(b0)&255)<<8)
         | ((unsigned)(q8(a1)&255)<<16) | ((unsigned)(q8(b1)&255)<<24);
}

// byte i (0..3) of u as signed int -> float
__device__ __forceinline__ float sb2f(unsigned u, int i){
    return (float)((int)(u << (24 - 8*i)) >> 24);
}

// decode one uint32 = 2 channels of (gx,gy) int8 pairs, fma into dx,dy
__device__ __forceinline__ void dec4(unsigned u, float rA, float rB,
                                     float& dx, float& dy){
    dx = fmaf(sb2f(u,0), rA, dx);
    dy = fmaf(sb2f(u,1), rA, dy);
    dx = fmaf(sb2f(u,2), rB, dx);
    dy = fmaf(sb2f(u,3), rB, dy);
}

__device__ __forceinline__ float4 ntload4(const float* p){
    vfloat4 v = __builtin_nontemporal_load(reinterpret_cast<const vfloat4*>(p));
    return make_float4(v.x, v.y, v.z, v.w);
}

// ---------------------------------------------------------------------------
// One-time prep (EXACT round-11 structure: 64-px tile, register transpose,
// NT input reads, write-merge-clean uint2 stores).
// ---------------------------------------------------------------------------
__global__ __launch_bounds__(256)
void pnp_prep(const float* __restrict__ fmap,
              const float* __restrict__ gxm,
              const float* __restrict__ gym,
              unsigned char* __restrict__ gQ,
              float* __restrict__ maps8)
{
    __shared__ float spart[4][5][64];      // 5,120 B
    const int tid = threadIdx.x;
    const int pq  = (tid & 15) * 4;        // pixel base within tile
    const int cqp = tid >> 4;              // channel-octet phase 0..15
    const int w   = tid >> 6;              // wave 0..3
    const size_t p0 = (size_t)blockIdx.x * 64;

    float acc[5][4];
    #pragma unroll
    for (int m=0;m<5;m++)
        #pragma unroll
        for (int i=0;i<4;i++) acc[m][i]=0.f;

    #pragma unroll
    for (int rep=0; rep<2; ++rep){
        const int c0 = cqp*8 + rep*4;          // 4 contiguous channels
        float4 gxv[4], gyv[4], fmv[4];
        #pragma unroll
        for (int j=0;j<4;j++){
            const size_t off = (size_t)(c0+j)*PLANE + p0 + pq;
            gxv[j] = ntload4(gxm  + off);
            gyv[j] = ntload4(gym  + off);
            fmv[j] = ntload4(fmap + off);
        }
        #pragma unroll
        for (int i=0;i<4;i++){                 // pixel within quad
            float a[4], b[4];
            #pragma unroll
            for (int j=0;j<4;j++){             // channel within group
                a[j] = f4e(gxv[j], i);
                b[j] = f4e(gyv[j], i);
                const float f = f4e(fmv[j], i);
                acc[0][i] = fmaf(a[j], f, acc[0][i]);
                acc[1][i] = fmaf(b[j], f, acc[1][i]);
                acc[2][i] = fmaf(a[j], a[j], acc[2][i]);
                acc[3][i] = fmaf(a[j], b[j], acc[3][i]);
                acc[4][i] = fmaf(b[j], b[j], acc[4][i]);
            }
            uint2 st;
            st.x = pack2(a[0], b[0], a[1], b[1]);
            st.y = pack2(a[2], b[2], a[3], b[3]);
            const size_t byteoff = (p0 + pq + i)*ROWB + (size_t)cqp*16 + rep*8;
            *reinterpret_cast<uint2*>(gQ + byteoff) = st;
        }
    }

    const bool lo16 = ((tid >> 4) & 3) == 0;
    #pragma unroll
    for (int m=0;m<5;m++){
        #pragma unroll
        for (int i=0;i<4;i++){
            float v = acc[m][i];
            v += __shfl_xor(v, 16);
            v += __shfl_xor(v, 32);
            if (lo16) spart[w][m][pq+i] = v;
        }
    }
    __syncthreads();

    if (tid < 64){
        const size_t pix = p0 + tid;
        const float m0 = spart[0][0][tid]+spart[1][0][tid]+spart[2][0][tid]+spart[3][0][tid];
        const float m1 = spart[0][1][tid]+spart[1][1][tid]+spart[2][1][tid]+spart[3][1][tid];
        const float m2 = spart[0][2][tid]+spart[1][2][tid]+spart[2][2][tid]+spart[3][2][tid];
        const float m3 = spart[0][3][tid]+spart[1][3][tid]+spart[2][3][tid]+spart[3][3][tid];
        const float m4 = spart[0][4][tid]+spart[1][4][tid]+spart[2][4][tid]+spart[3][4][tid];
        float4 v4; v4.x=m0; v4.y=m1; v4.z=m2; v4.w=m3;
        *reinterpret_cast<float4*>(&maps8[pix*MSTR]) = v4;
        maps8[pix*MSTR + 4] = m4;
    }
}

// ---------------------------------------------------------------------------
// Per-iteration accumulate: 2 lanes/point, 128 points/block, 256 blocks.
// Lane g covers channels [g*64, g*64+64): 16 fref float4 + 8 gQ uint4 loads
// in flight per lane; dx/dy accumulate in 4 independent FMA chains.
// Partials column-major: partials[col*NBLKA + blk].
// ---------------------------------------------------------------------------
__global__ __launch_bounds__(256)
void pnp_accum2(const float* __restrict__ pts3D,
                const float* __restrict__ fref,
                const unsigned char* __restrict__ gQ,
                const float* __restrict__ maps8,
                const float* __restrict__ Kmat,
                const float* __restrict__ Rsrc,
                const float* __restrict__ tsrc,
                float* __restrict__ partials)
{
    const int tid = threadIdx.x;
    const int g   = tid & 1;           // channel-64 lane
    const int pl  = tid >> 1;          // point slot 0..127
    const int n   = blockIdx.x * PPB + pl;

    // issue fref stream loads first -- independent of R,t chain
    const float4* rp = reinterpret_cast<const float4*>(fref + (size_t)n*CCH + g*64);
    float4 r[16];
    #pragma unroll
    for (int i=0;i<16;i++) r[i] = rp[i];

    const float R00=Rsrc[0],R01=Rsrc[1],R02=Rsrc[2];
    const float R10=Rsrc[3],R11=Rsrc[4],R12=Rsrc[5];
    const float R20=Rsrc[6],R21=Rsrc[7],R22=Rsrc[8];
    const float t0=tsrc[0],t1=tsrc[1],t2=tsrc[2];
    const float K00=Kmat[0],K01=Kmat[1],K02=Kmat[2];
    const float K10=Kmat[3],K11=Kmat[4],K12=Kmat[5];
    const float K20=Kmat[6],K21=Kmat[7],K22=Kmat[8];
    const float fx=K00, fy=K11;

    const float px=pts3D[n*3+0], py=pts3D[n*3+1], pz=pts3D[n*3+2];
    const float x = R00*px + R01*py + R02*pz + t0;
    const float y = R10*px + R11*py + R12*pz + t1;
    const float z = R20*px + R21*py + R22*pz + t2;
    const float phx = K00*x + K01*y + K02*z;
    const float phy = K10*x + K11*y + K12*z;
    const float phz = K20*x + K21*y + K22*z;
    const int p2x = (int)rintf(phx/phz) - 1;
    const int p2y = (int)rintf(phy/phz) - 1;
    const bool inb = (p2x>=0) && (p2y>=0) && (p2x<IMW) && (p2y<IMH);
    const int pix = inb ? (p2y*FMW + p2x) : 0;

    float dx=0.f, dy=0.f;
    if (inb) {
        const uint4* gp =
            reinterpret_cast<const uint4*>(gQ + (size_t)pix*ROWB + g*128);
        uint4 q[8];
        #pragma unroll
        for (int i=0;i<8;i++) q[i] = gp[i];
        // 4 independent FMA chains (16 fma each) to shorten the VALU path
        float dxa[4] = {0.f,0.f,0.f,0.f};
        float dya[4] = {0.f,0.f,0.f,0.f};
        #pragma unroll
        for (int i=0;i<8;i++){
            const int c = i & 3;
            dec4(q[i].x, r[2*i].x,   r[2*i].y,   dxa[c], dya[c]);
            dec4(q[i].y, r[2*i].z,   r[2*i].w,   dxa[c], dya[c]);
            dec4(q[i].z, r[2*i+1].x, r[2*i+1].y, dxa[c], dya[c]);
            dec4(q[i].w, r[2*i+1].z, r[2*i+1].w, dxa[c], dya[c]);
        }
        dx = ((dxa[0]+dxa[1]) + (dxa[2]+dxa[3])) * INVS;
        dy = ((dya[0]+dya[1]) + (dya[2]+dya[3])) * INVS;
    }
    // reduce dot products across the point's 2 lanes
    dx += __shfl_xor(dx, 1);
    dy += __shfl_xor(dy, 1);

    float v[NPART];
    #pragma unroll
    for (int i=0;i<NPART;i++) v[i]=0.f;
    if (inb) {
        const float4 m03 = *reinterpret_cast<const float4*>(&maps8[(size_t)pix*MSTR]);
        const float  m4  = maps8[(size_t)pix*MSTR + 4];
        const float sx  = m03.x - dx;
        const float sy  = m03.y - dy;
        const float gxx = m03.z;
        const float gxy = m03.w;
        const float gyy = m4;

        const float zi = 1.f/z;
        const float a0 = fx*zi;
        const float b0 = -fx*x*zi*zi;
        const float c1 = fy*zi;
        const float d1 = -fy*y*zi*zi;
        const float A0[6] = {a0, 0.f, b0, b0*y, a0*z - b0*x, -a0*y};
        const float A1[6] = {0.f, c1, d1, -c1*z + d1*y, -d1*x, c1*x};
        #pragma unroll
        for (int i=0;i<6;i++) v[i] = A0[i]*sx + A1[i]*sy;
        int idx=6;
        #pragma unroll
        for (int i=0;i<6;i++){
            #pragma unroll
            for (int j=i;j<6;j++){
                v[idx] = gxx*A0[i]*A0[j]
                       + gxy*(A0[i]*A1[j]+A1[i]*A0[j])
                       + gyy*A1[i]*A1[j];
                idx++;
            }
        }
    }

    // block reduce: xor2..32 folds the 32 points in this wave, LDS folds waves
    __shared__ float wpart[4][NPART];
    const int wid  = tid >> 6;
    const int lane = tid & 63;
    #pragma unroll
    for (int i=0;i<NPART;i++){
        float vv = v[i];
        vv += __shfl_xor(vv, 2);
        vv += __shfl_xor(vv, 4);
        vv += __shfl_xor(vv, 8);
        vv += __shfl_xor(vv, 16);
        vv += __shfl_xor(vv, 32);
        if (lane==0) wpart[wid][i]=vv;
    }
    __syncthreads();
    if (tid < NPART){
        partials[(size_t)tid*NBLKA + blockIdx.x] =
            wpart[0][tid]+wpart[1][tid]+wpart[2][tid]+wpart[3][tid];
    }
}

// ---------------------------------------------------------------------------
// Parallel-reduce column-major partials (8 threads/column, contiguous float4
// sweeps), damp, solve 6x6, so3exp, update R,t.
// ---------------------------------------------------------------------------
__global__ void pnp_solve(const float* __restrict__ partials,
                          const float* __restrict__ Rsrc,
                          const float* __restrict__ tsrc,
                          float* __restrict__ RtWs,
                          float* __restrict__ outp)
{
    __shared__ double red[NPART];
    const int t = threadIdx.x;
    if (t < NPART*8){
        const int col = t >> 3;
        const int k   = t & 7;
        const float4* p4 =
            reinterpret_cast<const float4*>(partials + (size_t)col*NBLKA) + k*8;
        double s = 0.0;
        #pragma unroll 4
        for (int i=0;i<8;i++){
            const float4 v = p4[i];
            s += (double)v.x + (double)v.y + (double)v.z + (double)v.w;
        }
        s += __shfl_xor(s, 1);
        s += __shfl_xor(s, 2);
        s += __shfl_xor(s, 4);
        if (k==0) red[col] = s;
    }
    __syncthreads();
    if (t==0){
        double gv[6]; double H[6][6];
        for (int i=0;i<6;i++) gv[i]=red[i];
        int idx=6;
        for (int i=0;i<6;i++)
            for (int j=i;j<6;j++){
                H[i][j]=red[idx]; H[j][i]=red[idx]; idx++;
            }
        for (int i=0;i<6;i++) H[i][i] += 0.01*(H[i][i] + 1e-9);

        double M[6][6], b[6];
        for (int i=0;i<6;i++){ b[i]=gv[i]; for (int j=0;j<6;j++) M[i][j]=H[i][j]; }
        for (int c=0;c<6;c++){
            int piv=c; double mx=fabs(M[c][c]);
            for (int r=c+1;r<6;r++){ double av=fabs(M[r][c]); if (av>mx){mx=av;piv=r;} }
            if (piv!=c){
                for (int j=c;j<6;j++){ double tmp=M[c][j]; M[c][j]=M[piv][j]; M[piv][j]=tmp; }
                double tb=b[c]; b[c]=b[piv]; b[piv]=tb;
            }
            const double inv = 1.0/M[c][c];
            for (int r=c+1;r<6;r++){
                const double f = M[r][c]*inv;
                for (int j=c;j<6;j++) M[r][j] -= f*M[c][j];
                b[r] -= f*b[c];
            }
        }
        double xs[6];
        for (int r=5;r>=0;r--){
            double s2=b[r];
            for (int j=r+1;j<6;j++) s2 -= M[r][j]*xs[j];
            xs[r]=s2/M[r][r];
        }
        double delta[6];
        for (int i=0;i<6;i++) delta[i] = -xs[i];

        const double wx=delta[3], wy=delta[4], wz=delta[5];
        const double th = sqrt(wx*wx+wy*wy+wz*wz + 1e-24);
        const double Ath = sin(th)/th;
        const double Bth = (1.0-cos(th))/(th*th);
        const double W[3][3] = {{0.0,-wz,wy},{wz,0.0,-wx},{-wy,wx,0.0}};
        double W2[3][3];
        for (int i=0;i<3;i++) for (int j=0;j<3;j++){
            double s2=0; for (int k2=0;k2<3;k2++) s2 += W[i][k2]*W[k2][j];
            W2[i][j]=s2;
        }
        double dR[3][3];
        for (int i=0;i<3;i++) for (int j=0;j<3;j++)
            dR[i][j] = (i==j?1.0:0.0) + Ath*W[i][j] + Bth*W2[i][j];

        double Ro[3][3];
        for (int i=0;i<3;i++) for (int j=0;j<3;j++) Ro[i][j]=(double)Rsrc[i*3+j];
        const double to0=(double)tsrc[0], to1=(double)tsrc[1], to2=(double)tsrc[2];

        double Rn[3][3], tn[3];
        for (int i=0;i<3;i++){
            for (int j=0;j<3;j++){
                double s2=0; for (int k2=0;k2<3;k2++) s2 += dR[i][k2]*Ro[k2][j];
                Rn[i][j]=s2;
            }
            tn[i] = dR[i][0]*to0 + dR[i][1]*to1 + dR[i][2]*to2 + delta[i];
        }
        for (int i=0;i<3;i++) for (int j=0;j<3;j++){
            RtWs[i*3+j] = (float)Rn[i][j];
            outp[i*3+j] = (float)Rn[i][j];
        }
        for (int i=0;i<3;i++){ RtWs[9+i]=(float)tn[i]; outp[9+i]=(float)tn[i]; }
    }
}

extern "C" void kernel_launch(void* const* d_in, const int* in_sizes, int n_in,
                              void* d_out, int out_size, void* d_ws, size_t ws_size,
                              hipStream_t stream)
{
    const float* pts   = (const float*)d_in[0];
    const float* fref  = (const float*)d_in[1];
    const float* fmap  = (const float*)d_in[2];
    const float* gxm   = (const float*)d_in[3];
    const float* gym   = (const float*)d_in[4];
    const float* Kmat  = (const float*)d_in[5];
    const float* Rin   = (const float*)d_in[6];
    const float* tin   = (const float*)d_in[7];
    float* outp = (float*)d_out;

    // ws: [partials(27*256)][RtWs(12)][maps8(8*PLANE)][gQ(PLANE*256B)]
    float* partials = (float*)d_ws;
    float* RtWs  = partials + (size_t)NPART*NBLKA;
    float* maps8 = RtWs + 12;
    unsigned char* gQ = reinterpret_cast<unsigned char*>(maps8 + (size_t)MSTR*PLANE);

    pnp_prep<<<PLANE/64, 256, 0, stream>>>(fmap, gxm, gym, gQ, maps8);

    const float* Rs = Rin;
    const float* ts = tin;
    for (int it=0; it<5; ++it){
        pnp_accum2<<<NBLKA, 256, 0, stream>>>(pts, fref, gQ, maps8,
                                              Kmat, Rs, ts, partials);
        pnp_solve<<<1, 256, 0, stream>>>(partials, Rs, ts, RtWs, outp);
        Rs = RtWs; ts = RtWs + 9;
    }
}

// Round 18
// 196.631 us; speedup vs baseline: 1.0704x; 1.0704x over previous
//
#include <hip/hip_runtime.h>
#include <math.h>

#define NPTS   32768
#define CCH    128
#define FMH    480
#define FMW    640
#define PLANE  (FMH*FMW)
#define IMW    640
#define IMH    480
#define PPB    64          // points per accum block (4 lanes/point) -- r16 optimum
#define NBLKA  (NPTS/PPB)  // 512 accum blocks
#define NPART  27          // 6 (g) + 21 (H upper triangle)
#define MSTR   8           // per-pixel map stride (floats)
#define ROWB   256         // gQ bytes per pixel row (128 ch x 2 int8)
#define SCL    200.0f      // grad int8 scale (|gx| max ~0.57 -> 114 < 127)
#define INVS   0.005f      // 1/SCL

typedef float vfloat4 __attribute__((ext_vector_type(4)));

__device__ __forceinline__ float f4e(const float4& v, int i){
    return i==0 ? v.x : i==1 ? v.y : i==2 ? v.z : v.w;
}

__device__ __forceinline__ int q8(float v){
    return (int)rintf(fminf(fmaxf(v*SCL, -127.f), 127.f));
}

__device__ __forceinline__ unsigned pack2(float a0,float b0,float a1,float b1){
    return (unsigned)(q8(a0)&255) | ((unsigned)(q8(b0)&255)<<8)
         | ((unsigned)(q8(a1)&255)<<16) | ((unsigned)(q8(b1)&255)<<24);
}

// byte i (0..3) of u as signed int -> float
__device__ __forceinline__ float sb2f(unsigned u, int i){
    return (float)((int)(u << (24 - 8*i)) >> 24);
}

// decode one uint32 = 2 channels of (gx,gy) int8 pairs, fma into dx,dy
__device__ __forceinline__ void dec4(unsigned u, float rA, float rB,
                                     float& dx, float& dy){
    dx = fmaf(sb2f(u,0), rA, dx);
    dy = fmaf(sb2f(u,1), rA, dy);
    dx = fmaf(sb2f(u,2), rB, dx);
    dy = fmaf(sb2f(u,3), rB, dy);
}

__device__ __forceinline__ float4 ntload4(const float* p){
    vfloat4 v = __builtin_nontemporal_load(reinterpret_cast<const vfloat4*>(p));
    return make_float4(v.x, v.y, v.z, v.w);
}

// ---------------------------------------------------------------------------
// One-time prep (round-11 structure: 64-px tile, register transpose,
// NT input reads, write-merge-clean uint2 stores). Measured floor:
// ~122 us at ~2.6 TB/s mixed-stream; seven variants all equal or worse.
// ---------------------------------------------------------------------------
__global__ __launch_bounds__(256)
void pnp_prep(const float* __restrict__ fmap,
              const float* __restrict__ gxm,
              const float* __restrict__ gym,
              unsigned char* __restrict__ gQ,
              float* __restrict__ maps8)
{
    __shared__ float spart[4][5][64];      // 5,120 B
    const int tid = threadIdx.x;
    const int pq  = (tid & 15) * 4;        // pixel base within tile
    const int cqp = tid >> 4;              // channel-octet phase 0..15
    const int w   = tid >> 6;              // wave 0..3
    const size_t p0 = (size_t)blockIdx.x * 64;

    float acc[5][4];
    #pragma unroll
    for (int m=0;m<5;m++)
        #pragma unroll
        for (int i=0;i<4;i++) acc[m][i]=0.f;

    #pragma unroll
    for (int rep=0; rep<2; ++rep){
        const int c0 = cqp*8 + rep*4;          // 4 contiguous channels
        float4 gxv[4], gyv[4], fmv[4];
        #pragma unroll
        for (int j=0;j<4;j++){
            const size_t off = (size_t)(c0+j)*PLANE + p0 + pq;
            gxv[j] = ntload4(gxm  + off);
            gyv[j] = ntload4(gym  + off);
            fmv[j] = ntload4(fmap + off);
        }
        #pragma unroll
        for (int i=0;i<4;i++){                 // pixel within quad
            float a[4], b[4];
            #pragma unroll
            for (int j=0;j<4;j++){             // channel within group
                a[j] = f4e(gxv[j], i);
                b[j] = f4e(gyv[j], i);
                const float f = f4e(fmv[j], i);
                acc[0][i] = fmaf(a[j], f, acc[0][i]);
                acc[1][i] = fmaf(b[j], f, acc[1][i]);
                acc[2][i] = fmaf(a[j], a[j], acc[2][i]);
                acc[3][i] = fmaf(a[j], b[j], acc[3][i]);
                acc[4][i] = fmaf(b[j], b[j], acc[4][i]);
            }
            uint2 st;
            st.x = pack2(a[0], b[0], a[1], b[1]);
            st.y = pack2(a[2], b[2], a[3], b[3]);
            const size_t byteoff = (p0 + pq + i)*ROWB + (size_t)cqp*16 + rep*8;
            *reinterpret_cast<uint2*>(gQ + byteoff) = st;
        }
    }

    const bool lo16 = ((tid >> 4) & 3) == 0;
    #pragma unroll
    for (int m=0;m<5;m++){
        #pragma unroll
        for (int i=0;i<4;i++){
            float v = acc[m][i];
            v += __shfl_xor(v, 16);
            v += __shfl_xor(v, 32);
            if (lo16) spart[w][m][pq+i] = v;
        }
    }
    __syncthreads();

    if (tid < 64){
        const size_t pix = p0 + tid;
        const float m0 = spart[0][0][tid]+spart[1][0][tid]+spart[2][0][tid]+spart[3][0][tid];
        const float m1 = spart[0][1][tid]+spart[1][1][tid]+spart[2][1][tid]+spart[3][1][tid];
        const float m2 = spart[0][2][tid]+spart[1][2][tid]+spart[2][2][tid]+spart[3][2][tid];
        const float m3 = spart[0][3][tid]+spart[1][3][tid]+spart[2][3][tid]+spart[3][3][tid];
        const float m4 = spart[0][4][tid]+spart[1][4][tid]+spart[2][4][tid]+spart[3][4][tid];
        float4 v4; v4.x=m0; v4.y=m1; v4.z=m2; v4.w=m3;
        *reinterpret_cast<float4*>(&maps8[pix*MSTR]) = v4;
        maps8[pix*MSTR + 4] = m4;
    }
}

// ---------------------------------------------------------------------------
// Per-iteration accumulate: 4 lanes/point, 64 points/block, 512 blocks.
// Lane g covers channels [g*32, g*32+32): 8 fref float4 + 4 gQ uint4 loads
// in flight per lane. fref issued BEFORE the projection chain.
// Partials column-major: partials[col*NBLKA + blk].  (r16 optimum: PPB 16/32
// /64 each won; 128 regressed to 1 block/CU.)
// ---------------------------------------------------------------------------
__global__ __launch_bounds__(256)
void pnp_accum2(const float* __restrict__ pts3D,
                const float* __restrict__ fref,
                const unsigned char* __restrict__ gQ,
                const float* __restrict__ maps8,
                const float* __restrict__ Kmat,
                const float* __restrict__ Rsrc,
                const float* __restrict__ tsrc,
                float* __restrict__ partials)
{
    const int tid = threadIdx.x;
    const int g   = tid & 3;           // channel-32 lane
    const int pl  = tid >> 2;          // point slot 0..63
    const int n   = blockIdx.x * PPB + pl;

    // issue fref stream loads first -- independent of R,t chain
    const float4* rp = reinterpret_cast<const float4*>(fref + (size_t)n*CCH + g*32);
    const float4 r0 = rp[0];
    const float4 r1 = rp[1];
    const float4 r2 = rp[2];
    const float4 r3 = rp[3];
    const float4 r4 = rp[4];
    const float4 r5 = rp[5];
    const float4 r6 = rp[6];
    const float4 r7 = rp[7];

    const float R00=Rsrc[0],R01=Rsrc[1],R02=Rsrc[2];
    const float R10=Rsrc[3],R11=Rsrc[4],R12=Rsrc[5];
    const float R20=Rsrc[6],R21=Rsrc[7],R22=Rsrc[8];
    const float t0=tsrc[0],t1=tsrc[1],t2=tsrc[2];
    const float K00=Kmat[0],K01=Kmat[1],K02=Kmat[2];
    const float K10=Kmat[3],K11=Kmat[4],K12=Kmat[5];
    const float K20=Kmat[6],K21=Kmat[7],K22=Kmat[8];
    const float fx=K00, fy=K11;

    const float px=pts3D[n*3+0], py=pts3D[n*3+1], pz=pts3D[n*3+2];
    const float x = R00*px + R01*py + R02*pz + t0;
    const float y = R10*px + R11*py + R12*pz + t1;
    const float z = R20*px + R21*py + R22*pz + t2;
    const float phx = K00*x + K01*y + K02*z;
    const float phy = K10*x + K11*y + K12*z;
    const float phz = K20*x + K21*y + K22*z;
    const int p2x = (int)rintf(phx/phz) - 1;
    const int p2y = (int)rintf(phy/phz) - 1;
    const bool inb = (p2x>=0) && (p2y>=0) && (p2x<IMW) && (p2y<IMH);
    const int pix = inb ? (p2y*FMW + p2x) : 0;

    float dx=0.f, dy=0.f;
    if (inb) {
        const uint4* gp =
            reinterpret_cast<const uint4*>(gQ + (size_t)pix*ROWB + g*64);
        const uint4 q0 = gp[0];
        const uint4 q1 = gp[1];
        const uint4 q2 = gp[2];
        const uint4 q3 = gp[3];
        dec4(q0.x, r0.x, r0.y, dx, dy);
        dec4(q0.y, r0.z, r0.w, dx, dy);
        dec4(q0.z, r1.x, r1.y, dx, dy);
        dec4(q0.w, r1.z, r1.w, dx, dy);
        dec4(q1.x, r2.x, r2.y, dx, dy);
        dec4(q1.y, r2.z, r2.w, dx, dy);
        dec4(q1.z, r3.x, r3.y, dx, dy);
        dec4(q1.w, r3.z, r3.w, dx, dy);
        dec4(q2.x, r4.x, r4.y, dx, dy);
        dec4(q2.y, r4.z, r4.w, dx, dy);
        dec4(q2.z, r5.x, r5.y, dx, dy);
        dec4(q2.w, r5.z, r5.w, dx, dy);
        dec4(q3.x, r6.x, r6.y, dx, dy);
        dec4(q3.y, r6.z, r6.w, dx, dy);
        dec4(q3.z, r7.x, r7.y, dx, dy);
        dec4(q3.w, r7.z, r7.w, dx, dy);
        dx *= INVS; dy *= INVS;
    }
    // reduce dot products across the point's 4 lanes
    #pragma unroll
    for (int d=1; d<4; d<<=1){
        dx += __shfl_xor(dx, d);
        dy += __shfl_xor(dy, d);
    }

    float v[NPART];
    #pragma unroll
    for (int i=0;i<NPART;i++) v[i]=0.f;
    if (inb) {
        const float4 m03 = *reinterpret_cast<const float4*>(&maps8[(size_t)pix*MSTR]);
        const float  m4  = maps8[(size_t)pix*MSTR + 4];
        const float sx  = m03.x - dx;
        const float sy  = m03.y - dy;
        const float gxx = m03.z;
        const float gxy = m03.w;
        const float gyy = m4;

        const float zi = 1.f/z;
        const float a0 = fx*zi;
        const float b0 = -fx*x*zi*zi;
        const float c1 = fy*zi;
        const float d1 = -fy*y*zi*zi;
        const float A0[6] = {a0, 0.f, b0, b0*y, a0*z - b0*x, -a0*y};
        const float A1[6] = {0.f, c1, d1, -c1*z + d1*y, -d1*x, c1*x};
        #pragma unroll
        for (int i=0;i<6;i++) v[i] = A0[i]*sx + A1[i]*sy;
        int idx=6;
        #pragma unroll
        for (int i=0;i<6;i++){
            #pragma unroll
            for (int j=i;j<6;j++){
                v[idx] = gxx*A0[i]*A0[j]
                       + gxy*(A0[i]*A1[j]+A1[i]*A0[j])
                       + gyy*A1[i]*A1[j];
                idx++;
            }
        }
    }

    // block reduce: xor4/8/16/32 folds the 16 points in this wave, LDS folds waves
    __shared__ float wpart[4][NPART];
    const int wid  = tid >> 6;
    const int lane = tid & 63;
    #pragma unroll
    for (int i=0;i<NPART;i++){
        float vv = v[i];
        vv += __shfl_xor(vv, 4);
        vv += __shfl_xor(vv, 8);
        vv += __shfl_xor(vv, 16);
        vv += __shfl_xor(vv, 32);
        if (lane==0) wpart[wid][i]=vv;
    }
    __syncthreads();
    if (tid < NPART){
        partials[(size_t)tid*NBLKA + blockIdx.x] =
            wpart[0][tid]+wpart[1][tid]+wpart[2][tid]+wpart[3][tid];
    }
}

// ---------------------------------------------------------------------------
// Parallel-reduce column-major partials (8 threads/column, contiguous float4
// sweeps), damp, solve 6x6, so3exp, update R,t.
// ---------------------------------------------------------------------------
__global__ void pnp_solve(const float* __restrict__ partials,
                          const float* __restrict__ Rsrc,
                          const float* __restrict__ tsrc,
                          float* __restrict__ RtWs,
                          float* __restrict__ outp)
{
    __shared__ double red[NPART];
    const int t = threadIdx.x;
    if (t < NPART*8){
        const int col = t >> 3;
        const int k   = t & 7;
        const float4* p4 =
            reinterpret_cast<const float4*>(partials + (size_t)col*NBLKA) + k*16;
        double s = 0.0;
        #pragma unroll 4
        for (int i=0;i<16;i++){
            const float4 v = p4[i];
            s += (double)v.x + (double)v.y + (double)v.z + (double)v.w;
        }
        s += __shfl_xor(s, 1);
        s += __shfl_xor(s, 2);
        s += __shfl_xor(s, 4);
        if (k==0) red[col] = s;
    }
    __syncthreads();
    if (t==0){
        double gv[6]; double H[6][6];
        for (int i=0;i<6;i++) gv[i]=red[i];
        int idx=6;
        for (int i=0;i<6;i++)
            for (int j=i;j<6;j++){
                H[i][j]=red[idx]; H[j][i]=red[idx]; idx++;
            }
        for (int i=0;i<6;i++) H[i][i] += 0.01*(H[i][i] + 1e-9);

        double M[6][6], b[6];
        for (int i=0;i<6;i++){ b[i]=gv[i]; for (int j=0;j<6;j++) M[i][j]=H[i][j]; }
        for (int c=0;c<6;c++){
            int piv=c; double mx=fabs(M[c][c]);
            for (int r=c+1;r<6;r++){ double av=fabs(M[r][c]); if (av>mx){mx=av;piv=r;} }
            if (piv!=c){
                for (int j=c;j<6;j++){ double tmp=M[c][j]; M[c][j]=M[piv][j]; M[piv][j]=tmp; }
                double tb=b[c]; b[c]=b[piv]; b[piv]=tb;
            }
            const double inv = 1.0/M[c][c];
            for (int r=c+1;r<6;r++){
                const double f = M[r][c]*inv;
                for (int j=c;j<6;j++) M[r][j] -= f*M[c][j];
                b[r] -= f*b[c];
            }
        }
        double xs[6];
        for (int r=5;r>=0;r--){
            double s2=b[r];
            for (int j=r+1;j<6;j++) s2 -= M[r][j]*xs[j];
            xs[r]=s2/M[r][r];
        }
        double delta[6];
        for (int i=0;i<6;i++) delta[i] = -xs[i];

        const double wx=delta[3], wy=delta[4], wz=delta[5];
        const double th = sqrt(wx*wx+wy*wy+wz*wz + 1e-24);
        const double Ath = sin(th)/th;
        const double Bth = (1.0-cos(th))/(th*th);
        const double W[3][3] = {{0.0,-wz,wy},{wz,0.0,-wx},{-wy,wx,0.0}};
        double W2[3][3];
        for (int i=0;i<3;i++) for (int j=0;j<3;j++){
            double s2=0; for (int k2=0;k2<3;k2++) s2 += W[i][k2]*W[k2][j];
            W2[i][j]=s2;
        }
        double dR[3][3];
        for (int i=0;i<3;i++) for (int j=0;j<3;j++)
            dR[i][j] = (i==j?1.0:0.0) + Ath*W[i][j] + Bth*W2[i][j];

        double Ro[3][3];
        for (int i=0;i<3;i++) for (int j=0;j<3;j++) Ro[i][j]=(double)Rsrc[i*3+j];
        const double to0=(double)tsrc[0], to1=(double)tsrc[1], to2=(double)tsrc[2];

        double Rn[3][3], tn[3];
        for (int i=0;i<3;i++){
            for (int j=0;j<3;j++){
                double s2=0; for (int k2=0;k2<3;k2++) s2 += dR[i][k2]*Ro[k2][j];
                Rn[i][j]=s2;
            }
            tn[i] = dR[i][0]*to0 + dR[i][1]*to1 + dR[i][2]*to2 + delta[i];
        }
        for (int i=0;i<3;i++) for (int j=0;j<3;j++){
            RtWs[i*3+j] = (float)Rn[i][j];
            outp[i*3+j] = (float)Rn[i][j];
        }
        for (int i=0;i<3;i++){ RtWs[9+i]=(float)tn[i]; outp[9+i]=(float)tn[i]; }
    }
}

extern "C" void kernel_launch(void* const* d_in, const int* in_sizes, int n_in,
                              void* d_out, int out_size, void* d_ws, size_t ws_size,
                              hipStream_t stream)
{
    const float* pts   = (const float*)d_in[0];
    const float* fref  = (const float*)d_in[1];
    const float* fmap  = (const float*)d_in[2];
    const float* gxm   = (const float*)d_in[3];
    const float* gym   = (const float*)d_in[4];
    const float* Kmat  = (const float*)d_in[5];
    const float* Rin   = (const float*)d_in[6];
    const float* tin   = (const float*)d_in[7];
    float* outp = (float*)d_out;

    // ws: [partials(27*512)][RtWs(12)][maps8(8*PLANE)][gQ(PLANE*256B)]
    float* partials = (float*)d_ws;
    float* RtWs  = partials + (size_t)NPART*NBLKA;
    float* maps8 = RtWs + 12;
    unsigned char* gQ = reinterpret_cast<unsigned char*>(maps8 + (size_t)MSTR*PLANE);

    pnp_prep<<<PLANE/64, 256, 0, stream>>>(fmap, gxm, gym, gQ, maps8);

    const float* Rs = Rin;
    const float* ts = tin;
    for (int it=0; it<5; ++it){
        pnp_accum2<<<NBLKA, 256, 0, stream>>>(pts, fref, gQ, maps8,
                                              Kmat, Rs, ts, partials);
        pnp_solve<<<1, 256, 0, stream>>>(partials, Rs, ts, RtWs, outp);
        Rs = RtWs; ts = RtWs + 9;
    }
}